// Round 1
// baseline (5380.911 us; speedup 1.0000x reference)
//
#include <hip/hip_runtime.h>

#define H   64
#define TT  1024
#define MB  8      // batch elements per workgroup
#define NW  512    // threads per workgroup
#define NWG 256    // workgroups (256*8 = 2048 = B)

__device__ __forceinline__ float fast_sigmoid(float x) {
    float e = __expf(-x);
    return __builtin_amdgcn_rcpf(1.0f + e);
}
__device__ __forceinline__ float fast_tanh(float x) {
    float xx = fminf(fmaxf(x, -15.0f), 15.0f);
    float e  = __expf(2.0f * xx);
    return (e - 1.0f) * __builtin_amdgcn_rcpf(e + 1.0f);
}

// Phase A: tids 0..287, matrix m = tid/96 in {w_hh0, w_ih1, w_hh1}, each thread
// owns rows gb and gb+96 in registers (128 VGPRs). h tiles live in LDS; reads are
// wave-broadcast (all lanes same address -> conflict-free).
// Phase B: all 512 threads, one (batch b, hidden j) gate task per layer.
// Layer 1 is pipelined one step behind layer 0.
__global__ __launch_bounds__(NW, 2) void gru_fused(
    const float* __restrict__ x,
    const float* __restrict__ w_ih0, const float* __restrict__ w_hh0,
    const float* __restrict__ b_ih0, const float* __restrict__ b_hh0,
    const float* __restrict__ w_ih1, const float* __restrict__ w_hh1,
    const float* __restrict__ b_ih1, const float* __restrict__ b_hh1,
    const float* __restrict__ w_fc,  const float* __restrict__ b_fc,
    float* __restrict__ out)
{
    __shared__ float h0[MB][H];
    __shared__ float h1[MB][H];
    __shared__ float gh0[MB][3*H];
    __shared__ float gx1[MB][3*H];
    __shared__ float gh1[MB][3*H];

    const int tid = threadIdx.x;
    const int b0g = blockIdx.x * MB;

    // ---- phase-A role ----
    const int m  = (tid < 288) ? (tid / 96) : 0;   // 0,1,2
    const int gb = tid % 96;
    const float* wmat = (m == 0) ? w_hh0 : (m == 1) ? w_ih1 : w_hh1;
    const float* bv   = (m == 0) ? b_hh0 : (m == 1) ? b_ih1 : b_hh1;
    const float (*hin)[H] = (m == 2) ? h1 : h0;    // m0,m1 read h0; m2 reads h1
    float (*gout)[3*H] = (m == 0) ? gh0 : (m == 1) ? gx1 : gh1;

    float w0[H], w1[H];
    float bias0 = 0.0f, bias1 = 0.0f;
    if (tid < 288) {
        #pragma unroll
        for (int k4 = 0; k4 < H/4; ++k4) {
            float4 a = *reinterpret_cast<const float4*>(wmat + gb*H + 4*k4);
            float4 b = *reinterpret_cast<const float4*>(wmat + (gb+96)*H + 4*k4);
            w0[4*k4+0]=a.x; w0[4*k4+1]=a.y; w0[4*k4+2]=a.z; w0[4*k4+3]=a.w;
            w1[4*k4+0]=b.x; w1[4*k4+1]=b.y; w1[4*k4+2]=b.z; w1[4*k4+3]=b.w;
        }
        bias0 = bv[gb]; bias1 = bv[gb+96];
    }

    // ---- phase-B per-thread constants ----
    const int bb = tid >> 6, jj = tid & 63;        // wave = one batch element
    const float wi0r = w_ih0[jj], wi0z = w_ih0[64+jj], wi0n = w_ih0[128+jj];
    const float bi0r = b_ih0[jj], bi0z = b_ih0[64+jj], bi0n = b_ih0[128+jj];
    const float wfc  = w_fc[jj];
    const float* xptr = x + (size_t)(b0g + bb) * TT;

    for (int i = tid; i < MB*H; i += NW) { (&h0[0][0])[i] = 0.0f; (&h1[0][0])[i] = 0.0f; }
    __syncthreads();

    for (int t = 0; t <= TT; ++t) {
        // ---- Phase A: three 192x64 matvecs for MB batch elements ----
        const bool activeA = (tid < 288) && ((m == 0) ? (t < TT) : (t >= 1));
        if (activeA) {
            float acc0[MB], acc1[MB];
            #pragma unroll
            for (int b = 0; b < MB; ++b) { acc0[b] = bias0; acc1[b] = bias1; }
            #pragma unroll
            for (int k4 = 0; k4 < H/4; ++k4) {
                #pragma unroll
                for (int b = 0; b < MB; ++b) {
                    const float4 h4 = *reinterpret_cast<const float4*>(&hin[b][4*k4]);
                    acc0[b] = fmaf(h4.x, w0[4*k4+0], acc0[b]);
                    acc0[b] = fmaf(h4.y, w0[4*k4+1], acc0[b]);
                    acc0[b] = fmaf(h4.z, w0[4*k4+2], acc0[b]);
                    acc0[b] = fmaf(h4.w, w0[4*k4+3], acc0[b]);
                    acc1[b] = fmaf(h4.x, w1[4*k4+0], acc1[b]);
                    acc1[b] = fmaf(h4.y, w1[4*k4+1], acc1[b]);
                    acc1[b] = fmaf(h4.z, w1[4*k4+2], acc1[b]);
                    acc1[b] = fmaf(h4.w, w1[4*k4+3], acc1[b]);
                }
            }
            #pragma unroll
            for (int b = 0; b < MB; ++b) { gout[b][gb] = acc0[b]; gout[b][gb+96] = acc1[b]; }
        }
        __syncthreads();

        // ---- Phase B: gates ----
        if (t < TT) {   // layer 0, step t
            float xv = xptr[t];
            float xr = fmaf(xv, wi0r, bi0r);
            float xz = fmaf(xv, wi0z, bi0z);
            float xn = fmaf(xv, wi0n, bi0n);
            float hr = gh0[bb][jj], hz = gh0[bb][64+jj], hn = gh0[bb][128+jj];
            float r = fast_sigmoid(xr + hr);
            float z = fast_sigmoid(xz + hz);
            float n = fast_tanh(fmaf(r, hn, xn));
            float ho = h0[bb][jj];
            h0[bb][jj] = fmaf(z, ho - n, n);       // (1-z)*n + z*h
        }
        if (t >= 1) {   // layer 1, step t-1 (gx1/gh1 already include biases)
            float xr = gx1[bb][jj], xz = gx1[bb][64+jj], xn = gx1[bb][128+jj];
            float hr = gh1[bb][jj], hz = gh1[bb][64+jj], hn = gh1[bb][128+jj];
            float r = fast_sigmoid(xr + hr);
            float z = fast_sigmoid(xz + hz);
            float n = fast_tanh(fmaf(r, hn, xn));
            float ho = h1[bb][jj];
            h1[bb][jj] = fmaf(z, ho - n, n);
        }
        __syncthreads();
    }

    // ---- final FC: out[b] = dot(h1[b], w_fc) + b_fc ----
    {
        float v = h1[bb][jj] * wfc;
        #pragma unroll
        for (int s = 32; s > 0; s >>= 1) v += __shfl_xor(v, s, 64);
        if (jj == 0) out[b0g + bb] = v + b_fc[0];
    }
}

extern "C" void kernel_launch(void* const* d_in, const int* in_sizes, int n_in,
                              void* d_out, int out_size, void* d_ws, size_t ws_size,
                              hipStream_t stream) {
    (void)in_sizes; (void)n_in; (void)out_size; (void)d_ws; (void)ws_size;
    gru_fused<<<NWG, NW, 0, stream>>>(
        (const float*)d_in[0],
        (const float*)d_in[1], (const float*)d_in[2],
        (const float*)d_in[3], (const float*)d_in[4],
        (const float*)d_in[5], (const float*)d_in[6],
        (const float*)d_in[7], (const float*)d_in[8],
        (const float*)d_in[9], (const float*)d_in[10],
        (float*)d_out);
}

// Round 2
// 1409.947 us; speedup vs baseline: 3.8164x; 3.8164x over previous
//
#include <hip/hip_runtime.h>

#define H    64
#define TT   1024
#define MB   8      // batch rows per workgroup
#define NW   512    // 8 waves
#define NWG  256
#define HS   68     // h LDS row stride (floats) — breaks stride-64 bank pathology
#define GS   192    // gate LDS row stride

typedef float          f32x4  __attribute__((ext_vector_type(4)));
typedef __bf16         bf16x8 __attribute__((ext_vector_type(8)));
typedef unsigned short us8    __attribute__((ext_vector_type(8)));

__device__ __forceinline__ unsigned short bf16_rne(float f) {
    unsigned u = __float_as_uint(f);
    u += 0x7FFFu + ((u >> 16) & 1u);
    return (unsigned short)(u >> 16);
}
__device__ __forceinline__ float fast_sigmoid(float x) {
    return __builtin_amdgcn_rcpf(1.0f + __expf(-x));
}
__device__ __forceinline__ float fast_tanh(float x) {
    float xx = fminf(fmaxf(x, -15.0f), 15.0f);
    float e  = __expf(2.0f * xx);
    return (e - 1.0f) * __builtin_amdgcn_rcpf(e + 1.0f);
}

// Per step (iter t):
//   G: gate1(t-1) [t>0] using gx1/gh1; gate0(t) using gh0 -> h0(t+1)=out0(t); write h to LDS
//   M: MFMA  gh0(t+1) = h0(t+1)@Whh0^T,  gx1(t) = out0(t)@Wih1^T,  gh1(t) = h1(t)@Whh1^T
// 36 N-tiles of 16: tiles 0-11 -> gh0, 12-23 -> gx1 (A = h0, waves 0-5, 4 tiles each),
//                   tiles 24-35 -> gh1 (A = h1, waves 6-7, 6 tiles each).
// Split-bf16: v = hi + lo; v*w ~= hi*whi + lo*whi + hi*wlo (3 MFMAs), fp32 accumulate.
__global__ __launch_bounds__(NW, 2) void gru_mfma(
    const float* __restrict__ x,
    const float* __restrict__ w_ih0, const float* __restrict__ w_hh0,
    const float* __restrict__ b_ih0, const float* __restrict__ b_hh0,
    const float* __restrict__ w_ih1, const float* __restrict__ w_hh1,
    const float* __restrict__ b_ih1, const float* __restrict__ b_hh1,
    const float* __restrict__ w_fc,  const float* __restrict__ b_fc,
    float* __restrict__ out)
{
    __shared__ float xs [MB * TT];     // 32 KB staged input
    __shared__ float gh0[MB * GS];
    __shared__ float gx1[MB * GS];
    __shared__ float gh1[MB * GS];
    __shared__ float h0s[16 * HS];     // rows 8-15 stay zero (MFMA A padding)
    __shared__ float h1s[16 * HS];

    const int tid  = threadIdx.x;
    const int wave = tid >> 6;
    const int lane = tid & 63;
    const int r    = lane & 15;        // MFMA: A-row / B-col / D-col
    const int q    = lane >> 4;        // MFMA: k-group / D row-group
    const int b0g  = blockIdx.x * MB;

    for (int i = tid; i < 16*HS; i += NW) { h0s[i] = 0.0f; h1s[i] = 0.0f; }
    for (int i = tid; i < MB*GS; i += NW) gh0[i] = 0.0f;

    // stage x: wave w copies batch row b0g+w (coalesced float4)
    {
        const float* xrow = x + (size_t)(b0g + wave) * TT;
        float* xd = xs + wave * TT;
        #pragma unroll
        for (int u = 0; u < 4; ++u) {
            int idx = (u * 64 + lane) * 4;
            *(float4*)(xd + idx) = *(const float4*)(xrow + idx);
        }
    }

    // ---- persistent B fragments (weights) in VGPRs ----
    int t0, nt;
    if (wave < 6) { t0 = 4 * wave;           nt = 4; }
    else          { t0 = 24 + 6 * (wave-6);  nt = 6; }

    bf16x8 bhi[6][2], blo[6][2];
    #pragma unroll
    for (int i = 0; i < 6; ++i) {
        if (i < nt) {
            const int n = t0 + i;
            const float* W; int g;
            if (n < 12)      { W = w_hh0; g = 16*n        + r; }
            else if (n < 24) { W = w_ih1; g = 16*(n-12)   + r; }
            else             { W = w_hh1; g = 16*(n-24)   + r; }
            #pragma unroll
            for (int c = 0; c < 2; ++c) {
                // lane supplies B[k][col]=W[g][k], k = 32c + 8q + j
                const float* wp = W + g*H + 32*c + 8*q;
                float4 p0 = *(const float4*)wp;
                float4 p1 = *(const float4*)(wp + 4);
                float f[8] = {p0.x,p0.y,p0.z,p0.w,p1.x,p1.y,p1.z,p1.w};
                us8 uh, ul;
                #pragma unroll
                for (int j = 0; j < 8; ++j) {
                    unsigned short h16 = bf16_rne(f[j]);
                    uh[j] = h16;
                    float fh = __uint_as_float((unsigned)h16 << 16);
                    ul[j] = bf16_rne(f[j] - fh);
                }
                bhi[i][c] = __builtin_bit_cast(bf16x8, uh);
                blo[i][c] = __builtin_bit_cast(bf16x8, ul);
            }
        }
    }

    // ---- per-thread gate constants (b = wave, j = lane) ----
    const float wi0r = w_ih0[lane], wi0z = w_ih0[64+lane], wi0n = w_ih0[128+lane];
    const float c0r  = b_ih0[lane]    + b_hh0[lane];
    const float c0z  = b_ih0[64+lane] + b_hh0[64+lane];
    const float bi0n = b_ih0[128+lane], bh0n = b_hh0[128+lane];
    const float c1r  = b_ih1[lane]    + b_hh1[lane];
    const float c1z  = b_ih1[64+lane] + b_hh1[64+lane];
    const float bi1n = b_ih1[128+lane], bh1n = b_hh1[128+lane];
    const float wfc  = w_fc[lane];

    float h0reg = 0.0f, h1reg = 0.0f;
    const float* xmy = xs  + wave * TT;
    const float* g0p = gh0 + wave * GS;
    const float* g1x = gx1 + wave * GS;
    const float* g1h = gh1 + wave * GS;
    float* h0w = h0s + wave * HS;
    float* h1w = h1s + wave * HS;

    __syncthreads();

    #pragma unroll 1
    for (int t = 0; t < TT; ++t) {
        // ---------------- G phase ----------------
        if (t > 0) {
            float xr = g1x[lane],     hr = g1h[lane];
            float xz = g1x[64+lane],  hz = g1h[64+lane];
            float xn = g1x[128+lane], hn = g1h[128+lane];
            float rr = fast_sigmoid(xr + hr + c1r);
            float zz = fast_sigmoid(xz + hz + c1z);
            float nn = fast_tanh(xn + bi1n + rr * (hn + bh1n));
            h1reg = fmaf(zz, h1reg - nn, nn);
            h1w[lane] = h1reg;
        }
        {
            float xv  = xmy[t];
            float g0r = g0p[lane], g0z = g0p[64+lane], g0n = g0p[128+lane];
            float rr = fast_sigmoid(fmaf(xv, wi0r, c0r) + g0r);
            float zz = fast_sigmoid(fmaf(xv, wi0z, c0z) + g0z);
            float nn = fast_tanh(fmaf(xv, wi0n, bi0n) + rr * (g0n + bh0n));
            h0reg = fmaf(zz, h0reg - nn, nn);
            h0w[lane] = h0reg;
        }
        __syncthreads();

        // ---------------- M phase ----------------
        {
            const float* hsrc = (wave < 6) ? h0s : h1s;
            bf16x8 ahi[2], alo[2];
            #pragma unroll
            for (int c = 0; c < 2; ++c) {
                // lane supplies A[row=r][k], k = 32c + 8q + j
                const float* hp = hsrc + r*HS + 32*c + 8*q;
                float4 p0 = *(const float4*)hp;
                float4 p1 = *(const float4*)(hp + 4);
                float f[8] = {p0.x,p0.y,p0.z,p0.w,p1.x,p1.y,p1.z,p1.w};
                us8 uh, ul;
                #pragma unroll
                for (int j = 0; j < 8; ++j) {
                    unsigned short h16 = bf16_rne(f[j]);
                    uh[j] = h16;
                    float fh = __uint_as_float((unsigned)h16 << 16);
                    ul[j] = bf16_rne(f[j] - fh);
                }
                ahi[c] = __builtin_bit_cast(bf16x8, uh);
                alo[c] = __builtin_bit_cast(bf16x8, ul);
            }
            #pragma unroll
            for (int i = 0; i < 6; ++i) {
                if (i < nt) {
                    const int n = t0 + i;
                    f32x4 d = {0.0f, 0.0f, 0.0f, 0.0f};
                    d = __builtin_amdgcn_mfma_f32_16x16x32_bf16(ahi[0], bhi[i][0], d, 0,0,0);
                    d = __builtin_amdgcn_mfma_f32_16x16x32_bf16(ahi[1], bhi[i][1], d, 0,0,0);
                    d = __builtin_amdgcn_mfma_f32_16x16x32_bf16(alo[0], bhi[i][0], d, 0,0,0);
                    d = __builtin_amdgcn_mfma_f32_16x16x32_bf16(alo[1], bhi[i][1], d, 0,0,0);
                    d = __builtin_amdgcn_mfma_f32_16x16x32_bf16(ahi[0], blo[i][0], d, 0,0,0);
                    d = __builtin_amdgcn_mfma_f32_16x16x32_bf16(ahi[1], blo[i][1], d, 0,0,0);
                    if (lane < 32) {   // D rows 0-7 only (batch); rows 8-15 are padding
                        float* dst; int cb;
                        if (n < 12)      { dst = gh0; cb = 16*n; }
                        else if (n < 24) { dst = gx1; cb = 16*(n-12); }
                        else             { dst = gh1; cb = 16*(n-24); }
                        float* p = dst + cb + r;
                        #pragma unroll
                        for (int k = 0; k < 4; ++k) p[(4*q + k) * GS] = d[k];
                    }
                }
            }
        }
        __syncthreads();
    }

    // final gate1(TT-1)
    {
        float xr = g1x[lane],     hr = g1h[lane];
        float xz = g1x[64+lane],  hz = g1h[64+lane];
        float xn = g1x[128+lane], hn = g1h[128+lane];
        float rr = fast_sigmoid(xr + hr + c1r);
        float zz = fast_sigmoid(xz + hz + c1z);
        float nn = fast_tanh(xn + bi1n + rr * (hn + bh1n));
        h1reg = fmaf(zz, h1reg - nn, nn);
    }
    // FC: out[b] = dot(h1, w_fc) + b_fc
    {
        float v = h1reg * wfc;
        #pragma unroll
        for (int s = 32; s > 0; s >>= 1) v += __shfl_xor(v, s, 64);
        if (lane == 0) out[b0g + wave] = v + b_fc[0];
    }
}

extern "C" void kernel_launch(void* const* d_in, const int* in_sizes, int n_in,
                              void* d_out, int out_size, void* d_ws, size_t ws_size,
                              hipStream_t stream) {
    (void)in_sizes; (void)n_in; (void)out_size; (void)d_ws; (void)ws_size;
    gru_mfma<<<NWG, NW, 0, stream>>>(
        (const float*)d_in[0],
        (const float*)d_in[1], (const float*)d_in[2],
        (const float*)d_in[3], (const float*)d_in[4],
        (const float*)d_in[5], (const float*)d_in[6],
        (const float*)d_in[7], (const float*)d_in[8],
        (const float*)d_in[9], (const float*)d_in[10],
        (float*)d_out);
}

// Round 3
// 972.490 us; speedup vs baseline: 5.5331x; 1.4498x over previous
//
#include <hip/hip_runtime.h>

#define H    64
#define TT   1024
#define MB   8      // batch rows per workgroup
#define NW   512    // 8 waves
#define NWG  256
#define GSP  584    // gate buffer row stride (floats); 584 % 32 == 8 -> 2-way-free D-writes

typedef float  f32x4  __attribute__((ext_vector_type(4)));
typedef __bf16 bf16x8 __attribute__((ext_vector_type(8)));

__device__ __forceinline__ unsigned short bf16_rne(float f) {
    unsigned u = __float_as_uint(f);
    u += 0x7FFFu + ((u >> 16) & 1u);
    return (unsigned short)(u >> 16);
}
__device__ __forceinline__ float fast_sigmoid(float x) {
    return __builtin_amdgcn_rcpf(1.0f + __expf(-x));
}
__device__ __forceinline__ float fast_tanh(float x) {
    float xx = fminf(fmaxf(x, -15.0f), 15.0f);
    float e  = __expf(2.0f * xx);
    return (e - 1.0f) * __builtin_amdgcn_rcpf(e + 1.0f);
}

// gA cols: [0,192) = gh0 = h0@Whh0^T ; [192,384) = gx1 = out0@Wih1^T ; [384,576) = gh1 = h1@Whh1^T
// global gate col of tile n is 16n for all three (192 = 16*12, 384 = 16*24).
// hA: [16 rows][128 bf16] — rows 0-7 = h0 batch, rows 8-15 = h1 batch; cols 0-63 hi, 64-127 lo.
//     XOR-swizzled in 16B chunks: phys_chunk = logical_chunk ^ (row & 7).
// 40 tiles, 5 per wave (tiles >= 36 are dummies on wave 7: MFMA issued, write suppressed).
// Split-bf16: v*w ~= hi*whi + lo*whi + hi*wlo (3 MFMAs per K-chunk, fp32 accumulate).
__global__ __launch_bounds__(NW, 2) void gru_mfma2(
    const float* __restrict__ x,
    const float* __restrict__ w_ih0, const float* __restrict__ w_hh0,
    const float* __restrict__ b_ih0, const float* __restrict__ b_hh0,
    const float* __restrict__ w_ih1, const float* __restrict__ w_hh1,
    const float* __restrict__ b_ih1, const float* __restrict__ b_hh1,
    const float* __restrict__ w_fc,  const float* __restrict__ b_fc,
    float* __restrict__ out)
{
    __shared__ float          xs[MB * TT];      // 32 KB
    __shared__ float          gA[MB * GSP];     // 18.25 KB
    __shared__ unsigned short hA[16 * 128];     // 4 KB

    const int tid  = threadIdx.x;
    const int wave = tid >> 6;
    const int lane = tid & 63;
    const int r    = lane & 15;        // A row / D col
    const int q    = lane >> 4;        // k-group / D row-group
    const int b0g  = blockIdx.x * MB;

    for (int i = tid; i < 16*128; i += NW) hA[i] = 0;
    for (int i = tid; i < MB*GSP; i += NW) gA[i] = 0.0f;

    // stage x: wave w copies batch row b0g+w (coalesced float4)
    {
        const float* xrow = x + (size_t)(b0g + wave) * TT;
        float* xd = xs + wave * TT;
        #pragma unroll
        for (int u = 0; u < 4; ++u) {
            int idx = (u * 64 + lane) * 4;
            *(float4*)(xd + idx) = *(const float4*)(xrow + idx);
        }
    }

    // ---- persistent B fragments (weights), uniform 5 tiles/wave ----
    bf16x8 bhi[5][2], blo[5][2];
    int   doff [5];     // gA offset for D row k=0 (deref only when wr_ok)
    bool  wr_ok[5];
    #pragma unroll
    for (int i = 0; i < 5; ++i) {
        const int n = 5 * wave + i;
        const float* W; int gr;
        if      (n < 12) { W = w_hh0; gr = 16 * n; }
        else if (n < 24) { W = w_ih1; gr = 16 * (n - 12); }
        else if (n < 36) { W = w_hh1; gr = 16 * (n - 24); }
        else             { W = w_hh0; gr = 0; }
        #pragma unroll
        for (int c = 0; c < 2; ++c) {
            const float* wp = W + (gr + r) * H + 32 * c + 8 * q;
            float4 p0 = *(const float4*)wp;
            float4 p1 = *(const float4*)(wp + 4);
            float f[8] = {p0.x,p0.y,p0.z,p0.w,p1.x,p1.y,p1.z,p1.w};
            unsigned short uh[8], ul[8];
            #pragma unroll
            for (int j = 0; j < 8; ++j) {
                unsigned short h16 = bf16_rne(f[j]);
                uh[j] = h16;
                ul[j] = bf16_rne(f[j] - __uint_as_float((unsigned)h16 << 16));
            }
            bhi[i][c] = *(const bf16x8*)uh;
            blo[i][c] = *(const bf16x8*)ul;
        }
        const int rowoff = (n < 24) ? 0 : 8;
        doff [i] = (4*q - rowoff) * GSP + 16*n + r;
        wr_ok[i] = (n < 36) && ((n < 24) ? (lane < 32) : (lane >= 32));
    }

    // ---- loop-invariant pointers ----
    const int s2 = r & 7;
    const unsigned short* hrow = hA + r * 128;
    const unsigned short* aP0 = hrow + (((0 + q) ^ s2) << 3);   // hi, k-chunk 0
    const unsigned short* aP1 = hrow + (((4 + q) ^ s2) << 3);   // hi, k-chunk 1
    const unsigned short* aP2 = aP0 + 64;                       // lo, k-chunk 0
    const unsigned short* aP3 = aP1 + 64;                       // lo, k-chunk 1

    const int chnk = lane >> 3, coff = lane & 7;
    unsigned short* p0h = hA + wave * 128 + ((chnk ^ wave) << 3) + coff;  // (wave&7)==wave
    unsigned short* p0l = p0h + 64;
    unsigned short* p1h = p0h + 8 * 128;
    unsigned short* p1l = p1h + 64;

    const float* gp  = gA + wave * GSP;
    const float* xmy = xs + wave * TT;

    // ---- gate constants (wave = batch, lane = hidden j) ----
    const float wi0r = w_ih0[lane], wi0z = w_ih0[64+lane], wi0n = w_ih0[128+lane];
    const float c0r  = b_ih0[lane]     + b_hh0[lane];
    const float c0z  = b_ih0[64+lane]  + b_hh0[64+lane];
    const float bi0n = b_ih0[128+lane], bh0n = b_hh0[128+lane];
    const float c1r  = b_ih1[lane]     + b_hh1[lane];
    const float c1z  = b_ih1[64+lane]  + b_hh1[64+lane];
    const float bi1n = b_ih1[128+lane], bh1n = b_hh1[128+lane];
    const float wfc  = w_fc[lane];

    float h0reg = 0.0f, h1reg = 0.0f;
    __syncthreads();

    #pragma unroll 1
    for (int t = 0; t < TT; ++t) {
        // ---------------- G phase ----------------
        if (t > 0) {            // layer 1, step t-1
            float xr = gp[192+lane], xz = gp[256+lane], xn = gp[320+lane];
            float hr = gp[384+lane], hz = gp[448+lane], hn = gp[512+lane];
            float rr = fast_sigmoid(xr + hr + c1r);
            float zz = fast_sigmoid(xz + hz + c1z);
            float nn = fast_tanh(xn + bi1n + rr * (hn + bh1n));
            h1reg = fmaf(zz, h1reg - nn, nn);
            unsigned short hh = bf16_rne(h1reg);
            *p1h = hh;
            *p1l = bf16_rne(h1reg - __uint_as_float((unsigned)hh << 16));
        }
        {                        // layer 0, step t
            float xv  = xmy[t];
            float g0r = gp[lane], g0z = gp[64+lane], g0n = gp[128+lane];
            float rr = fast_sigmoid(fmaf(xv, wi0r, c0r) + g0r);
            float zz = fast_sigmoid(fmaf(xv, wi0z, c0z) + g0z);
            float nn = fast_tanh(fmaf(xv, wi0n, bi0n) + rr * (g0n + bh0n));
            h0reg = fmaf(zz, h0reg - nn, nn);
            unsigned short hh = bf16_rne(h0reg);
            *p0h = hh;
            *p0l = bf16_rne(h0reg - __uint_as_float((unsigned)hh << 16));
        }
        __syncthreads();

        // ---------------- M phase ----------------
        {
            bf16x8 ahi0 = *(const bf16x8*)aP0;
            bf16x8 ahi1 = *(const bf16x8*)aP1;
            bf16x8 alo0 = *(const bf16x8*)aP2;
            bf16x8 alo1 = *(const bf16x8*)aP3;
            #pragma unroll
            for (int i = 0; i < 5; ++i) {
                f32x4 d = {0.0f, 0.0f, 0.0f, 0.0f};
                d = __builtin_amdgcn_mfma_f32_16x16x32_bf16(ahi0, bhi[i][0], d, 0,0,0);
                d = __builtin_amdgcn_mfma_f32_16x16x32_bf16(ahi1, bhi[i][1], d, 0,0,0);
                d = __builtin_amdgcn_mfma_f32_16x16x32_bf16(alo0, bhi[i][0], d, 0,0,0);
                d = __builtin_amdgcn_mfma_f32_16x16x32_bf16(alo1, bhi[i][1], d, 0,0,0);
                d = __builtin_amdgcn_mfma_f32_16x16x32_bf16(ahi0, blo[i][0], d, 0,0,0);
                d = __builtin_amdgcn_mfma_f32_16x16x32_bf16(ahi1, blo[i][1], d, 0,0,0);
                if (wr_ok[i]) {
                    float* p = gA + doff[i];
                    p[0*GSP] = d[0]; p[1*GSP] = d[1]; p[2*GSP] = d[2]; p[3*GSP] = d[3];
                }
            }
        }
        __syncthreads();
    }

    // final layer-1 gate (step TT-1)
    {
        float xr = gp[192+lane], xz = gp[256+lane], xn = gp[320+lane];
        float hr = gp[384+lane], hz = gp[448+lane], hn = gp[512+lane];
        float rr = fast_sigmoid(xr + hr + c1r);
        float zz = fast_sigmoid(xz + hz + c1z);
        float nn = fast_tanh(xn + bi1n + rr * (hn + bh1n));
        h1reg = fmaf(zz, h1reg - nn, nn);
    }
    // FC: out[b] = dot(h1, w_fc) + b_fc
    {
        float v = h1reg * wfc;
        #pragma unroll
        for (int s = 32; s > 0; s >>= 1) v += __shfl_xor(v, s, 64);
        if (lane == 0) out[b0g + wave] = v + b_fc[0];
    }
}

extern "C" void kernel_launch(void* const* d_in, const int* in_sizes, int n_in,
                              void* d_out, int out_size, void* d_ws, size_t ws_size,
                              hipStream_t stream) {
    (void)in_sizes; (void)n_in; (void)out_size; (void)d_ws; (void)ws_size;
    gru_mfma2<<<NWG, NW, 0, stream>>>(
        (const float*)d_in[0],
        (const float*)d_in[1], (const float*)d_in[2],
        (const float*)d_in[3], (const float*)d_in[4],
        (const float*)d_in[5], (const float*)d_in[6],
        (const float*)d_in[7], (const float*)d_in[8],
        (const float*)d_in[9], (const float*)d_in[10],
        (float*)d_out);
}